// Round 2
// baseline (238.775 us; speedup 1.0000x reference)
//
#include <hip/hip_runtime.h>

using bf16 = __bf16;
typedef __attribute__((ext_vector_type(8))) __bf16 bf16x8;
typedef __attribute__((ext_vector_type(4))) float f32x4;

#define NB 8
#define CC 512
#define LL 2048
#define IC 256
#define NLTOT 16384

__device__ inline bf16 f2bf(float f) {
    unsigned u = __builtin_bit_cast(unsigned, f);
    unsigned r = (u + 0x7fff + ((u >> 16) & 1)) >> 16;
    return __builtin_bit_cast(bf16, (unsigned short)r);
}

// ---------------- ws layout (bytes) ----------------
static constexpr size_t oScale = 0;                       // 8192 B
static constexpr size_t oWT    = 8192;                    // thetaT,phiT,gT (each 256x512 bf16), WwT (512x256 bf16)
static constexpr size_t oAn    = oWT + 4ull * 262144;     // 16 MB
static constexpr size_t oBn    = oAn + 16777216ull;       // 16 MB
static constexpr size_t oQ     = oBn + 16777216ull;       // 8 MB
static constexpr size_t oK     = oQ + 8388608ull;         // 8 MB
static constexpr size_t oVT    = oK + 8388608ull;         // 8 MB
static constexpr size_t oY     = oVT + 8388608ull;        // 8 MB
static constexpr size_t oProj  = oY + 8388608ull;         // 32 MB fp32

// ---------------- weight prep: transpose + bf16 ----------------
__global__ __launch_bounds__(256) void prep_weights(
    const float* __restrict__ theta_w, const float* __restrict__ phi_w,
    const float* __restrict__ g_w, const float* __restrict__ W_w,
    bf16* __restrict__ wts)
{
    int idx = blockIdx.x * 256 + threadIdx.x;   // 4 * 131072 total
    int which = idx >> 17;
    int o = idx & 131071;
    float v;
    if (which < 3) {
        const float* W = which == 0 ? theta_w : (which == 1 ? phi_w : g_w);
        int ic = o >> 9, cc = o & 511;          // out [ic][cc]
        v = W[cc * IC + ic];
    } else {
        int cc = o >> 8, ic = o & 255;          // out [cc][ic]
        v = W_w[ic * CC + cc];
    }
    wts[(size_t)which * 131072 + o] = f2bf(v);
}

// ---------------- BN stats ----------------
__global__ __launch_bounds__(256) void bn_stats(
    const float* __restrict__ A, const float* __restrict__ B,
    const float* __restrict__ gamma, const float* __restrict__ beta,
    float* __restrict__ scaleshift)
{
    int bid = blockIdx.x;
    int tensor = bid >> 9, c = bid & 511;
    const float* X = tensor ? B : A;
    int t = threadIdx.x;
    float s = 0.f, sq = 0.f;
    for (int n = 0; n < NB; ++n) {
        const float* row = &X[((size_t)(n * CC + c)) << 11];
        for (int j = t * 4; j < LL; j += 1024) {
            float4 v = *(const float4*)&row[j];
            s += v.x + v.y + v.z + v.w;
            sq += v.x * v.x + v.y * v.y + v.z * v.z + v.w * v.w;
        }
    }
    __shared__ float rs[256], rq[256];
    rs[t] = s; rq[t] = sq;
    __syncthreads();
    for (int step = 128; step > 0; step >>= 1) {
        if (t < step) { rs[t] += rs[t + step]; rq[t] += rq[t + step]; }
        __syncthreads();
    }
    if (t == 0) {
        float mean = rs[0] * (1.f / 16384.f);
        float var = rq[0] * (1.f / 16384.f) - mean * mean;
        float rsq = rsqrtf(var + 1e-5f);
        float sc = gamma[c] * rsq;
        scaleshift[tensor * 1024 + c] = sc;
        scaleshift[tensor * 1024 + 512 + c] = beta[c] - mean * sc;
    }
}

// ---------------- BN apply + ReLU + transpose -> bf16 [N,L,C] ----------------
__global__ __launch_bounds__(256) void bn_apply_transpose(
    const float* __restrict__ X, const float* __restrict__ scale,
    const float* __restrict__ shift, bf16* __restrict__ Out)
{
    int bidx = blockIdx.x;                  // NB * 8 * 32
    int lt = bidx & 31, ct = (bidx >> 5) & 7, n = bidx >> 8;
    int c0 = ct * 64, l0 = lt * 64;
    __shared__ float tile[64][65];          // [c][l]
    int t = threadIdx.x;
    #pragma unroll
    for (int i = 0; i < 4; ++i) {
        int r = i * 16 + (t >> 4);
        int c4 = (t & 15) * 4;
        float s = scale[c0 + r], sh = shift[c0 + r];
        float4 v = *(const float4*)&X[(((size_t)n * CC + c0 + r) << 11) + l0 + c4];
        tile[r][c4 + 0] = fmaxf(v.x * s + sh, 0.f);
        tile[r][c4 + 1] = fmaxf(v.y * s + sh, 0.f);
        tile[r][c4 + 2] = fmaxf(v.z * s + sh, 0.f);
        tile[r][c4 + 3] = fmaxf(v.w * s + sh, 0.f);
    }
    __syncthreads();
    #pragma unroll
    for (int i = 0; i < 2; ++i) {
        int lr = i * 32 + (t >> 3);
        int c8 = (t & 7) * 8;
        bf16 tmp[8];
        #pragma unroll
        for (int e = 0; e < 8; ++e) tmp[e] = f2bf(tile[c8 + e][lr]);
        *(bf16x8*)&Out[(((size_t)(n << 11)) + l0 + lr) * CC + c0 + c8] = *(bf16x8*)tmp;
    }
}

// ---------------- MFMA GEMM: C[M,N] = A[M,K] @ BT[N,K]^T + bias ----------------
// EPI 0: bf16 row-major; EPI 1: bf16 batch-transposed (vT [8][256][2048]); EPI 2: fp32 row-major
template<int EPI>
__global__ __launch_bounds__(256) void gemm_bt(
    const bf16* __restrict__ A, const bf16* __restrict__ BT,
    const float* __restrict__ bias, void* __restrict__ Cout,
    int M, int Nn, int K, int nTilesN)
{
    int bid = blockIdx.x;
    int tn = bid % nTilesN, tm = bid / nTilesN;
    int m0 = tm * 128, n0 = tn * 128;
    __shared__ bf16 a_lds[128][72];
    __shared__ bf16 b_lds[128][72];
    int t = threadIdx.x;
    int l = t & 63, w = t >> 6;
    int wr = w >> 1, wc = w & 1;
    f32x4 acc[4][4] = {};
    for (int k0 = 0; k0 < K; k0 += 64) {
        __syncthreads();
        #pragma unroll
        for (int i = 0; i < 4; ++i) {
            int ci = t + i * 256;
            int row = ci >> 3, c8 = (ci & 7) * 8;
            *(bf16x8*)&a_lds[row][c8] = *(const bf16x8*)&A[(size_t)(m0 + row) * K + k0 + c8];
            *(bf16x8*)&b_lds[row][c8] = *(const bf16x8*)&BT[(size_t)(n0 + row) * K + k0 + c8];
        }
        __syncthreads();
        #pragma unroll
        for (int ks = 0; ks < 2; ++ks) {
            bf16x8 af[4], bfr[4];
            #pragma unroll
            for (int mi = 0; mi < 4; ++mi)
                af[mi] = *(const bf16x8*)&a_lds[wr * 64 + mi * 16 + (l & 15)][ks * 32 + (l >> 4) * 8];
            #pragma unroll
            for (int ni = 0; ni < 4; ++ni)
                bfr[ni] = *(const bf16x8*)&b_lds[wc * 64 + ni * 16 + (l & 15)][ks * 32 + (l >> 4) * 8];
            #pragma unroll
            for (int mi = 0; mi < 4; ++mi)
                #pragma unroll
                for (int ni = 0; ni < 4; ++ni)
                    acc[mi][ni] = __builtin_amdgcn_mfma_f32_16x16x32_bf16(af[mi], bfr[ni], acc[mi][ni], 0, 0, 0);
        }
    }
    #pragma unroll
    for (int mi = 0; mi < 4; ++mi)
        #pragma unroll
        for (int ni = 0; ni < 4; ++ni) {
            int col = n0 + wc * 64 + ni * 16 + (l & 15);
            float bv = bias[col];
            #pragma unroll
            for (int r = 0; r < 4; ++r) {
                int row = m0 + wr * 64 + mi * 16 + (l >> 4) * 4 + r;
                float v = acc[mi][ni][r] + bv;
                if (EPI == 0) {
                    ((bf16*)Cout)[(size_t)row * Nn + col] = f2bf(v);
                } else if (EPI == 1) {
                    int b = row >> 11, li = row & 2047;
                    ((bf16*)Cout)[((size_t)(b * IC + col) << 11) + li] = f2bf(v);
                } else {
                    ((float*)Cout)[(size_t)row * Nn + col] = v;
                }
            }
        }
}

// ---------------- fused flash attention ----------------
// Q,K: [8][2048][256] bf16 ; VT: [8][256][2048] bf16 ; Y: [8][2048][256] bf16
__global__ __launch_bounds__(256) void flash_attn(
    const bf16* __restrict__ Q, const bf16* __restrict__ Kmat,
    const bf16* __restrict__ VT, bf16* __restrict__ Y)
{
    int bidx = blockIdx.x;                  // 8 * 32
    int nb = bidx >> 5;
    int qt = bidx & 31;
    int t = threadIdx.x, l = t & 63, w = t >> 6;
    int q0 = qt * 64 + w * 16;
    const bf16* Qn = Q + (((size_t)nb) << 11) * IC;
    const bf16* Kn = Kmat + (((size_t)nb) << 11) * IC;
    const bf16* Vn = VT + (size_t)nb * IC * LL;
    __shared__ bf16 k_lds[32][264];
    __shared__ bf16 v_lds[256][40];
    __shared__ bf16 p_lds[4][16][40];

    bf16x8 qf[8];
    {
        const bf16* qrow = Qn + (size_t)(q0 + (l & 15)) * IC + (l >> 4) * 8;
        #pragma unroll
        for (int s = 0; s < 8; ++s) qf[s] = *(const bf16x8*)(qrow + s * 32);
    }
    f32x4 o[16] = {};
    float mrow[4] = { -__builtin_inff(), -__builtin_inff(), -__builtin_inff(), -__builtin_inff() };
    float ell[4] = {};

    for (int kt = 0; kt < LL; kt += 32) {
        __syncthreads();
        #pragma unroll
        for (int i = 0; i < 4; ++i) {       // K tile: 32 x 256
            int ci = t + i * 256;
            int row = ci >> 5, c8 = (ci & 31) * 8;
            *(bf16x8*)&k_lds[row][c8] = *(const bf16x8*)&Kn[(size_t)(kt + row) * IC + c8];
        }
        #pragma unroll
        for (int i = 0; i < 4; ++i) {       // VT tile: 256 x 32
            int ci = t + i * 256;
            int row = ci >> 2, c8 = (ci & 3) * 8;
            *(bf16x8*)&v_lds[row][c8] = *(const bf16x8*)&Vn[((size_t)row << 11) + kt + c8];
        }
        __syncthreads();

        f32x4 sc0 = {}, sc1 = {};
        #pragma unroll
        for (int s = 0; s < 8; ++s) {
            bf16x8 kf0 = *(const bf16x8*)&k_lds[(l & 15)][s * 32 + (l >> 4) * 8];
            bf16x8 kf1 = *(const bf16x8*)&k_lds[16 + (l & 15)][s * 32 + (l >> 4) * 8];
            sc0 = __builtin_amdgcn_mfma_f32_16x16x32_bf16(qf[s], kf0, sc0, 0, 0, 0);
            sc1 = __builtin_amdgcn_mfma_f32_16x16x32_bf16(qf[s], kf1, sc1, 0, 0, 0);
        }

        #pragma unroll
        for (int r = 0; r < 4; ++r) {
            float tm = fmaxf(sc0[r], sc1[r]);
            #pragma unroll
            for (int off = 1; off < 16; off <<= 1) tm = fmaxf(tm, __shfl_xor(tm, off));
            float nm = fmaxf(mrow[r], tm);
            float fac = __expf(mrow[r] - nm);
            mrow[r] = nm;
            float p0 = __expf(sc0[r] - nm), p1 = __expf(sc1[r] - nm);
            float ts = p0 + p1;
            #pragma unroll
            for (int off = 1; off < 16; off <<= 1) ts += __shfl_xor(ts, off);
            ell[r] = ell[r] * fac + ts;
            int rr = (l >> 4) * 4 + r;
            p_lds[w][rr][(l & 15)] = f2bf(p0);
            p_lds[w][rr][16 + (l & 15)] = f2bf(p1);
            #pragma unroll
            for (int f = 0; f < 16; ++f) o[f][r] *= fac;
        }
        __syncthreads();

        bf16x8 pa = *(const bf16x8*)&p_lds[w][(l & 15)][(l >> 4) * 8];
        #pragma unroll
        for (int f = 0; f < 16; ++f) {
            bf16x8 vb = *(const bf16x8*)&v_lds[f * 16 + (l & 15)][(l >> 4) * 8];
            o[f] = __builtin_amdgcn_mfma_f32_16x16x32_bf16(pa, vb, o[f], 0, 0, 0);
        }
    }

    #pragma unroll
    for (int r = 0; r < 4; ++r) {
        int row = q0 + (l >> 4) * 4 + r;
        float inv = 1.0f / ell[r];
        #pragma unroll
        for (int f = 0; f < 16; ++f)
            Y[((((size_t)nb) << 11) + row) * IC + f * 16 + (l & 15)] = f2bf(o[f][r] * inv);
    }
}

// ---------------- final: out = relu(A*sc+sh) + proj^T ----------------
__global__ __launch_bounds__(256) void final_out(
    const float* __restrict__ A, const float* __restrict__ scaleshift,
    const float* __restrict__ proj, float* __restrict__ Out)
{
    int bidx = blockIdx.x;                  // NB * 8 * 32
    int lt = bidx & 31, ct = (bidx >> 5) & 7, n = bidx >> 8;
    int c0 = ct * 64, l0 = lt * 64;
    __shared__ float tile[64][65];          // [l][c]
    int t = threadIdx.x;
    #pragma unroll
    for (int i = 0; i < 4; ++i) {
        int lr = i * 16 + (t >> 4);
        int c4 = (t & 15) * 4;
        float4 v = *(const float4*)&proj[((((size_t)n) << 11) + l0 + lr) * CC + c0 + c4];
        tile[lr][c4 + 0] = v.x; tile[lr][c4 + 1] = v.y;
        tile[lr][c4 + 2] = v.z; tile[lr][c4 + 3] = v.w;
    }
    __syncthreads();
    #pragma unroll
    for (int i = 0; i < 4; ++i) {
        int cr = i * 16 + (t >> 4);
        int l4 = (t & 15) * 4;
        int c = c0 + cr;
        float s = scaleshift[c], sh = scaleshift[512 + c];
        float4 a = *(const float4*)&A[(((size_t)n * CC + c) << 11) + l0 + l4];
        float4 r;
        r.x = fmaxf(a.x * s + sh, 0.f) + tile[l4 + 0][cr];
        r.y = fmaxf(a.y * s + sh, 0.f) + tile[l4 + 1][cr];
        r.z = fmaxf(a.z * s + sh, 0.f) + tile[l4 + 2][cr];
        r.w = fmaxf(a.w * s + sh, 0.f) + tile[l4 + 3][cr];
        *(float4*)&Out[(((size_t)n * CC + c) << 11) + l0 + l4] = r;
    }
}

extern "C" void kernel_launch(void* const* d_in, const int* in_sizes, int n_in,
                              void* d_out, int out_size, void* d_ws, size_t ws_size,
                              hipStream_t stream) {
    const float* A       = (const float*)d_in[0];
    const float* B       = (const float*)d_in[1];
    const float* gamma   = (const float*)d_in[2];
    const float* beta    = (const float*)d_in[3];
    const float* theta_w = (const float*)d_in[4];
    const float* theta_b = (const float*)d_in[5];
    const float* phi_w   = (const float*)d_in[6];
    const float* phi_b   = (const float*)d_in[7];
    const float* g_w     = (const float*)d_in[8];
    const float* g_b     = (const float*)d_in[9];
    const float* W_w     = (const float*)d_in[10];
    const float* W_b     = (const float*)d_in[11];
    float* Out = (float*)d_out;

    char* ws = (char*)d_ws;
    float* scaleshift = (float*)(ws + oScale);
    bf16* wts    = (bf16*)(ws + oWT);
    bf16* thetaT = wts;
    bf16* phiT   = wts + 131072;
    bf16* gT     = wts + 2 * 131072;
    bf16* WwT    = wts + 3 * 131072;
    bf16* An = (bf16*)(ws + oAn);
    bf16* Bn = (bf16*)(ws + oBn);
    bf16* q  = (bf16*)(ws + oQ);
    bf16* k  = (bf16*)(ws + oK);
    bf16* vT = (bf16*)(ws + oVT);
    bf16* y  = (bf16*)(ws + oY);
    float* proj = (float*)(ws + oProj);

    prep_weights<<<2048, 256, 0, stream>>>(theta_w, phi_w, g_w, W_w, wts);
    bn_stats<<<1024, 256, 0, stream>>>(A, B, gamma, beta, scaleshift);
    bn_apply_transpose<<<2048, 256, 0, stream>>>(A, scaleshift + 0,    scaleshift + 512,  An);
    bn_apply_transpose<<<2048, 256, 0, stream>>>(B, scaleshift + 1024, scaleshift + 1536, Bn);

    gemm_bt<0><<<256, 256, 0, stream>>>(An, thetaT, theta_b, q,  NLTOT, IC, CC, 2);
    gemm_bt<0><<<256, 256, 0, stream>>>(Bn, phiT,   phi_b,   k,  NLTOT, IC, CC, 2);
    gemm_bt<1><<<256, 256, 0, stream>>>(An, gT,     g_b,     vT, NLTOT, IC, CC, 2);

    flash_attn<<<256, 256, 0, stream>>>(q, k, vT, y);

    gemm_bt<2><<<512, 256, 0, stream>>>(y, WwT, W_b, proj, NLTOT, CC, IC, 4);

    final_out<<<2048, 256, 0, stream>>>(A, scaleshift, proj, Out);
}